// Round 2
// 1749.049 us; speedup vs baseline: 4.3420x; 4.3420x over previous
//
#include <hip/hip_runtime.h>

typedef unsigned short u16;
typedef unsigned int u32;

#define DD 256

typedef short  s16x8 __attribute__((ext_vector_type(8)));
typedef short  s16x4 __attribute__((ext_vector_type(4)));
typedef float  f32x4 __attribute__((ext_vector_type(4)));

__device__ __forceinline__ float b2f(u16 u){
  union { u32 i; float f; } c; c.i = ((u32)u) << 16; return c.f;
}
// round-to-nearest-even f32 -> bf16 (finite inputs)
__device__ __forceinline__ u16 f2b(float f){
  union { float f; u32 i; } c; c.f = f;
  u32 b = c.i + 0x7FFFu + ((c.i >> 16) & 1u);
  return (u16)(b >> 16);
}

// keep the harness's expected symbol name alive
__global__ void NodeEncoder_72971494359603_kernel(){}

// ---------------- dtype probe ----------------
__global__ void probe_dtype(const u32* w, u32* flag){
  if (threadIdx.x == 0 && blockIdx.x == 0){
    int cnt = 0;
    for (int i = 0; i < 256; i++){
      u32 low = w[i] & 0xFFFFu;
      u32 e = (low >> 7) & 0xFFu;
      if (e >= 0x60u && e <= 0x7Eu) cnt++;
    }
    *flag = (cnt >= 192) ? 1u : 0u;
  }
}

__global__ void cvt_in(const void* src, u16* dst, int n, const u32* flag){
  int i = blockIdx.x * 256 + threadIdx.x;
  if (i < n){
    if (*flag){
      dst[i] = ((const u16*)src)[i];
    } else {
      dst[i] = f2b(((const float*)src)[i]);
    }
  }
}

__global__ void store_out(const u16* h, void* dout, int n, const u32* flag){
  int i = blockIdx.x * 256 + threadIdx.x;
  if (i < n){
    if (*flag){
      ((u16*)dout)[i] = h[i];
    } else {
      ((float*)dout)[i] = b2f(h[i]);
    }
  }
}

// ---------------- utility ----------------
__global__ void zero_int(int* p, int n){
  int i = blockIdx.x * 256 + threadIdx.x;
  if (i < n) p[i] = 0;
}

// TBL[(l*18 + a*3 + b)*256 + j] = ee1[l][a][j] + ee2[l][b][j]   (f32)
__global__ void build_table(const u16* ee1, const u16* ee2, float* TBL){
  int b = blockIdx.x;               // 0..89
  int l = b / 18, c = b % 18, a = c / 3, bb = c % 3;
  int j = threadIdx.x;
  TBL[b * DD + j] = b2f(ee1[(l * 6 + a) * DD + j]) + b2f(ee2[(l * 3 + bb) * DD + j]);
}

// ---------------- CSR build ----------------
__global__ void hist_kernel(const int* dst, int* counts, int E){
  int e = blockIdx.x * 256 + threadIdx.x;
  if (e < E) atomicAdd(&counts[dst[e]], 1);
}

__global__ void scan_sums(const int* counts, int* bsum, int N){
  __shared__ int red[256];
  int tid = threadIdx.x;
  int base = blockIdx.x * 1024;
  int s = 0;
  for (int i = tid; i < 1024; i += 256){
    int g = base + i;
    if (g < N) s += counts[g];
  }
  red[tid] = s;
  __syncthreads();
  for (int off = 128; off > 0; off >>= 1){
    if (tid < off) red[tid] += red[tid + off];
    __syncthreads();
  }
  if (tid == 0) bsum[blockIdx.x] = red[0];
}

__global__ void scan_top(int* bsum, int nb){
  if (threadIdx.x == 0 && blockIdx.x == 0){
    int acc = 0;
    for (int i = 0; i < nb; i++){ int t = bsum[i]; bsum[i] = acc; acc += t; }
  }
}

__global__ void scan_block(const int* counts, const int* bsum,
                           int* offsets, int* cursor, int N){
  __shared__ int tsum[256];
  int b = blockIdx.x;
  int tid = threadIdx.x;
  int base = b * 1024;
  int v0, v1, v2, v3;
  int g = base + tid * 4;
  v0 = (g + 0 < N) ? counts[g + 0] : 0;
  v1 = (g + 1 < N) ? counts[g + 1] : 0;
  v2 = (g + 2 < N) ? counts[g + 2] : 0;
  v3 = (g + 3 < N) ? counts[g + 3] : 0;
  tsum[tid] = v0 + v1 + v2 + v3;
  __syncthreads();
  for (int off = 1; off < 256; off <<= 1){
    int t = (tid >= off) ? tsum[tid - off] : 0;
    __syncthreads();
    tsum[tid] += t;
    __syncthreads();
  }
  int excl = (tid == 0 ? 0 : tsum[tid - 1]) + bsum[b];
  if (g + 0 < N){ offsets[g + 0] = excl; cursor[g + 0] = excl; } excl += v0;
  if (g + 1 < N){ offsets[g + 1] = excl; cursor[g + 1] = excl; } excl += v1;
  if (g + 2 < N){ offsets[g + 2] = excl; cursor[g + 2] = excl; } excl += v2;
  if (g + 3 < N){ offsets[g + 3] = excl; cursor[g + 3] = excl; }
}

// payload[pos] = src | ((ea0*3+ea1) << 17)
__global__ void fill_csr(const int* ei, const int* ea, int* cursor,
                         int* payload, int E){
  int e = blockIdx.x * 256 + threadIdx.x;
  if (e < E){
    int d = ei[E + e];
    int pos = atomicAdd(&cursor[d], 1);
    int a = ea[2 * e], bb = ea[2 * e + 1];
    payload[pos] = ei[e] | ((a * 3 + bb) << 17);
  }
}

// ---------------- node embedding ----------------
__global__ void node_embed(const int* x, const u16* xe1, const u16* xe2,
                           u16* out, int N){
  int idx = blockIdx.x * 256 + threadIdx.x;
  if (idx < N * DD){
    int n = idx >> 8, j = idx & 255;
    int x0 = x[2 * n], x1 = x[2 * n + 1];
    out[idx] = f2b(b2f(xe1[x0 * DD + j]) + b2f(xe2[x1 * DD + j]));
  }
}

// ---------------- aggregation (CSR gather-sum, vectorized) ----------------
// wave-per-node, lane handles 4 consecutive cols: 8B feature gathers,
// 16B LDS table reads.
__global__ void aggregate(const u16* __restrict__ feat, const float* __restrict__ TBL,
                          const int* __restrict__ offsets, const int* __restrict__ counts,
                          const int* __restrict__ payload, u16* __restrict__ agg, int N){
  __shared__ __align__(16) float T[18 * DD];
  int tid = threadIdx.x;
  for (int i = tid; i < 18 * DD; i += 256) T[i] = TBL[i];
  __syncthreads();
  int wave = tid >> 6, lane = tid & 63;
  int c4 = lane * 4;
  int n0 = blockIdx.x * 32 + wave * 8;
  for (int u = 0; u < 8; u++){
    int n = n0 + u;
    if (n >= N) return;
    s16x4 sv = *(const s16x4*)(feat + (size_t)n * DD + c4);
    f32x4 tb = *(const f32x4*)(T + 12 * DD + c4);    // self-loop (4,0) -> idx 12
    float a0 = b2f((u16)sv[0]) + tb[0];
    float a1 = b2f((u16)sv[1]) + tb[1];
    float a2 = b2f((u16)sv[2]) + tb[2];
    float a3 = b2f((u16)sv[3]) + tb[3];
    int e0 = offsets[n], cnt = counts[n];
    for (int e = e0; e < e0 + cnt; e++){
      int pl = payload[e];
      int src = pl & 0x1FFFF;
      int idx = pl >> 17;
      s16x4 rv = *(const s16x4*)(feat + (size_t)src * DD + c4);
      f32x4 tv = *(const f32x4*)(T + idx * DD + c4);
      a0 += b2f((u16)rv[0]) + tv[0];
      a1 += b2f((u16)rv[1]) + tv[1];
      a2 += b2f((u16)rv[2]) + tv[2];
      a3 += b2f((u16)rv[3]) + tv[3];
    }
    s16x4 o;
    o[0] = (short)f2b(a0); o[1] = (short)f2b(a1);
    o[2] = (short)f2b(a2); o[3] = (short)f2b(a3);
    *(s16x4*)(agg + (size_t)n * DD + c4) = o;
  }
}

// ---------------- B packing for MFMA fragments ----------------
// Wp chunk layout: frag = (cblk*(K/32) + ksub); lane l of frag holds
// W[ksub*32 + (l>>4)*8 + e][cblk*16 + (l&15)], e=0..7  (16B per lane,
// lane-contiguous -> one coalesced global_load_dwordx4 per b-frag).
__global__ void pack_B(const u16* __restrict__ W, u16* __restrict__ Wp, int K, int Nc){
  int idx = blockIdx.x * 256 + threadIdx.x;
  int lane = idx & 63;
  int t = idx >> 6;
  int nk = K >> 5;
  int ksub = t % nk, cblk = t / nk;
  if (cblk >= (Nc >> 4)) return;
  int col = cblk * 16 + (lane & 15);
  int krow = ksub * 32 + (lane >> 4) * 8;
  u16* dst = Wp + (size_t)idx * 8;
#pragma unroll
  for (int e = 0; e < 8; e++)
    dst[e] = W[(size_t)(krow + e) * Nc + col];
}

// ---------------- MFMA bf16 GEMM ----------------
// C[M,Nc] = relu?(A[M,K] @ W[K,Nc] + bias). 128x128 tile, 256 threads
// (4 waves in 2x2), each wave 64x64 via 4x4 fragments of
// v_mfma_f32_16x16x32_bf16 (builtin: compiler handles MFMA hazards +
// waitcnts). A staged in LDS with 16B-chunk XOR swizzle; B read as
// pre-packed fragments straight from L2.
__global__ void gemm_mfma(const u16* __restrict__ A, const u16* __restrict__ Wp,
                          const u16* __restrict__ bias, u16* __restrict__ C,
                          int M, int K, int Nc, int relu){
  __shared__ __align__(16) u16 As[128 * 64];   // 16 KB, swizzled
  int tid = threadIdx.x;
  int lane = tid & 63;
  int wave = tid >> 6;
  int wr = wave >> 1, wc = wave & 1;
  int row0 = blockIdx.x * 128;
  int col0 = blockIdx.y * 128;
  int lrow = lane & 15;          // fragment row (A) / col (B,C)
  int lk8 = (lane >> 4) * 8;     // fragment k-offset

  // staging geometry: thread covers 4 chunks of 16B (8 bf16)
  int srow = tid >> 3;           // row within a 32-row group
  int slot = tid & 7;            // 16B chunk within the 128B row
  int xslot = slot ^ (srow & 7); // write-side swizzle
  int nkb = K >> 5;
  int cb0 = (col0 >> 4) + wc * 4;

  f32x4 zero = {0.f, 0.f, 0.f, 0.f};
  f32x4 acc[4][4];
#pragma unroll
  for (int m = 0; m < 4; m++)
#pragma unroll
    for (int n = 0; n < 4; n++) acc[m][n] = zero;

  for (int ks = 0; ks < K; ks += 64){
    // global A loads (unswizzled columns), issued before the barrier
    s16x8 stg[4];
#pragma unroll
    for (int i = 0; i < 4; i++){
      int r = row0 + i * 32 + srow;
      if (r > M - 1) r = M - 1;              // clamp: valid bf16, rows >=M never stored
      stg[i] = *(const s16x8*)(A + (size_t)r * K + ks + slot * 8);
    }
    // B fragments for this k-step: one 16B coalesced load each (L2-resident)
    s16x8 bfr[2][4];
    int ks5 = ks >> 5;
#pragma unroll
    for (int kk = 0; kk < 2; kk++)
#pragma unroll
      for (int n = 0; n < 4; n++){
        size_t fidx = ((size_t)(cb0 + n) * nkb + ks5 + kk) * 64 + lane;
        bfr[kk][n] = *(const s16x8*)(Wp + fidx * 8);
      }
    __syncthreads();   // previous iteration's ds_reads complete
#pragma unroll
    for (int i = 0; i < 4; i++){
      int byteoff = (i * 32 + srow) * 128 + (xslot << 4);
      *(s16x8*)((char*)As + byteoff) = stg[i];
    }
    __syncthreads();   // staging visible
#pragma unroll
    for (int kk = 0; kk < 2; kk++){
      s16x8 afr[4];
#pragma unroll
      for (int m = 0; m < 4; m++){
        int arow = wr * 64 + m * 16 + lrow;
        int boff = arow * 128 + ((((kk * 32 + lk8) * 2)) ^ ((arow & 7) << 4));
        afr[m] = *(const s16x8*)((const char*)As + boff);
      }
#pragma unroll
      for (int m = 0; m < 4; m++)
#pragma unroll
        for (int n = 0; n < 4; n++)
          acc[m][n] = __builtin_amdgcn_mfma_f32_16x16x32_bf16(
              afr[m], bfr[kk][n], acc[m][n], 0, 0, 0);
    }
  }

  // epilogue: bias + optional relu, bf16 store
  int r4 = (lane >> 4) * 4;
  float bv[4];
#pragma unroll
  for (int n = 0; n < 4; n++) bv[n] = b2f(bias[col0 + wc * 64 + n * 16 + lrow]);
#pragma unroll
  for (int m = 0; m < 4; m++){
    int rb = row0 + wr * 64 + m * 16 + r4;
#pragma unroll
    for (int r = 0; r < 4; r++){
      int row = rb + r;
      if (row >= M) continue;
      u16* cp = C + (size_t)row * Nc + col0 + wc * 64 + lrow;
#pragma unroll
      for (int n = 0; n < 4; n++){
        float v = acc[m][n][r] + bv[n];
        if (relu && v < 0.f) v = 0.f;
        cp[n * 16] = f2b(v);
      }
    }
  }
}

// ---------------- BatchNorm (vectorized) ----------------
#define SBLK 256
__global__ void bn_stats(const u16* __restrict__ h, float* __restrict__ partial,
                         int N, int rpb){
  __shared__ float redS[8][256];
  __shared__ float redQ[8][256];
  int t = threadIdx.x;
  int rl = t >> 5, cg = (t & 31) * 8;
  int r0 = blockIdx.x * rpb;
  int r1 = r0 + rpb; if (r1 > N) r1 = N;
  float s[8], q[8];
#pragma unroll
  for (int e = 0; e < 8; e++){ s[e] = 0.f; q[e] = 0.f; }
  for (int r = r0 + rl; r < r1; r += 8){
    s16x8 v = *(const s16x8*)(h + (size_t)r * DD + cg);
#pragma unroll
    for (int e = 0; e < 8; e++){
      float f = b2f((u16)v[e]);
      s[e] += f; q[e] += f * f;
    }
  }
#pragma unroll
  for (int e = 0; e < 8; e++){ redS[rl][cg + e] = s[e]; redQ[rl][cg + e] = q[e]; }
  __syncthreads();
  float a = 0.f, b = 0.f;
#pragma unroll
  for (int k = 0; k < 8; k++){ a += redS[k][t]; b += redQ[k][t]; }
  partial[(size_t)blockIdx.x * DD + t] = a;
  partial[(size_t)(SBLK + blockIdx.x) * DD + t] = b;
}

__global__ void bn_reduce(const float* __restrict__ partial, float* __restrict__ sums){
  int j = threadIdx.x;
  int which = blockIdx.x;      // 0 = sum, 1 = sumsq
  float s = 0.f;
  for (int i = 0; i < SBLK; i++)
    s += partial[(size_t)(which * SBLK + i) * DD + j];
  sums[which * DD + j] = s;
}

__global__ void bn_apply(const u16* __restrict__ h, const float* __restrict__ sums,
                         const u16* __restrict__ gamma, const u16* __restrict__ beta,
                         u16* __restrict__ out, int N, float invN){
  int t = threadIdx.x;
  int rl = t >> 5, cg = (t & 31) * 8;
  float sc[8], sh[8];
#pragma unroll
  for (int e = 0; e < 8; e++){
    int j = cg + e;
    float mean = sums[j] * invN;
    float var = sums[DD + j] * invN - mean * mean;
    if (var < 0.f) var = 0.f;
    float scl = rsqrtf(var + 1e-5f) * b2f(gamma[j]);
    sc[e] = scl; sh[e] = b2f(beta[j]) - mean * scl;
  }
  for (int r = blockIdx.x * 8 + rl; r < N; r += gridDim.x * 8){
    s16x8 v = *(const s16x8*)(h + (size_t)r * DD + cg);
    s16x8 o;
#pragma unroll
    for (int e = 0; e < 8; e++){
      float f = b2f((u16)v[e]) * sc[e] + sh[e];
      if (f < 0.f) f = 0.f;
      o[e] = (short)f2b(f);
    }
    *(s16x8*)(out + (size_t)r * DD + cg) = o;
  }
}

// ---------------- host ----------------
extern "C" void kernel_launch(void* const* d_in, const int* in_sizes, int n_in,
                              void* d_out, int out_size, void* d_ws, size_t ws_size,
                              hipStream_t stream){
  (void)n_in; (void)out_size;
  const int* x    = (const int*)d_in[0];
  const int* ei   = (const int*)d_in[1];
  const int* ea   = (const int*)d_in[2];
  const void* xe1 = d_in[3];
  const void* xe2 = d_in[4];
  const void* ee1 = d_in[5];
  const void* ee2 = d_in[6];
  const void* W1  = d_in[7];
  const void* b1  = d_in[8];
  const void* W2  = d_in[9];
  const void* b2  = d_in[10];
  const void* gam = d_in[11];
  const void* bet = d_in[12];

  int N = in_sizes[0] / 2;
  int E = in_sizes[1] / 2;
  int NB = (N + 1023) / 1024;
  const int L = 5;

  // manual workspace carve (256B aligned)
  char* base = (char*)d_ws;
  size_t off = 0;
  u32* flag    = (u32*)(base + off);   off += 256;
  float* TBL   = (float*)(base + off); off += ((size_t)L * 18 * DD * 4 + 255) & ~(size_t)255;
  int* counts  = (int*)(base + off);   off += ((size_t)N * 4 + 255) & ~(size_t)255;
  int* offsets = (int*)(base + off);   off += ((size_t)N * 4 + 255) & ~(size_t)255;
  int* cursor  = (int*)(base + off);   off += ((size_t)N * 4 + 255) & ~(size_t)255;
  int* bsum    = (int*)(base + off);   off += ((size_t)NB * 4 + 255) & ~(size_t)255;
  int* payload = (int*)(base + off);   off += ((size_t)E * 4 + 255) & ~(size_t)255;
  float* part  = (float*)(base + off); off += ((size_t)2 * SBLK * DD * 4 + 255) & ~(size_t)255;
  float* sums  = (float*)(base + off); off += ((size_t)2 * DD * 4 + 255) & ~(size_t)255;
  // bf16 working copies of float inputs
  u16* wx1  = (u16*)(base + off); off += ((size_t)120 * DD * 2 + 255) & ~(size_t)255;
  u16* wx2  = (u16*)(base + off); off += ((size_t)3 * DD * 2 + 255) & ~(size_t)255;
  u16* wee1 = (u16*)(base + off); off += ((size_t)L * 6 * DD * 2 + 255) & ~(size_t)255;
  u16* wee2 = (u16*)(base + off); off += ((size_t)L * 3 * DD * 2 + 255) & ~(size_t)255;
  u16* wW1  = (u16*)(base + off); off += ((size_t)L * DD * 2 * DD * 2 + 255) & ~(size_t)255;
  u16* wb1  = (u16*)(base + off); off += ((size_t)L * 2 * DD * 2 + 255) & ~(size_t)255;
  u16* wW2  = (u16*)(base + off); off += ((size_t)L * 2 * DD * DD * 2 + 255) & ~(size_t)255;
  u16* wb2  = (u16*)(base + off); off += ((size_t)L * DD * 2 + 255) & ~(size_t)255;
  u16* wgam = (u16*)(base + off); off += ((size_t)(L - 1) * DD * 2 + 255) & ~(size_t)255;
  u16* wbet = (u16*)(base + off); off += ((size_t)(L - 1) * DD * 2 + 255) & ~(size_t)255;
  // packed MFMA B fragments
  u16* Wp1  = (u16*)(base + off); off += ((size_t)L * DD * 2 * DD * 2 + 255) & ~(size_t)255;
  u16* Wp2  = (u16*)(base + off); off += ((size_t)L * 2 * DD * DD * 2 + 255) & ~(size_t)255;
  // big feature buffers (bf16)
  u16* feat = (u16*)(base + off); off += ((size_t)N * DD * 2 + 255) & ~(size_t)255;
  u16* agg  = (u16*)(base + off); off += ((size_t)N * DD * 2 + 255) & ~(size_t)255;
  // mid chunk sized to fit remaining workspace
  size_t remain = (ws_size > off + 4096) ? (ws_size - off - 4096) : 0;
  long long chv = (long long)(remain / ((size_t)2 * DD * 2));  // bytes per mid row = 512*2
  int CH = (int)(chv < 2048 ? 2048 : (chv > 32768 ? 32768 : chv));
  CH &= ~127;
  if (CH > N) CH = (N + 127) & ~127;
  u16* mid = (u16*)(base + off); off += (size_t)CH * 2 * DD * 2;

  // dtype probe + input conversion to bf16 working copies
  probe_dtype<<<1, 64, 0, stream>>>((const u32*)xe1, flag);
  cvt_in<<<(120 * DD + 255) / 256, 256, 0, stream>>>(xe1, wx1, 120 * DD, flag);
  cvt_in<<<(3 * DD + 255) / 256, 256, 0, stream>>>(xe2, wx2, 3 * DD, flag);
  cvt_in<<<(L * 6 * DD + 255) / 256, 256, 0, stream>>>(ee1, wee1, L * 6 * DD, flag);
  cvt_in<<<(L * 3 * DD + 255) / 256, 256, 0, stream>>>(ee2, wee2, L * 3 * DD, flag);
  cvt_in<<<(L * DD * 2 * DD + 255) / 256, 256, 0, stream>>>(W1, wW1, L * DD * 2 * DD, flag);
  cvt_in<<<(L * 2 * DD + 255) / 256, 256, 0, stream>>>(b1, wb1, L * 2 * DD, flag);
  cvt_in<<<(L * 2 * DD * DD + 255) / 256, 256, 0, stream>>>(W2, wW2, L * 2 * DD * DD, flag);
  cvt_in<<<(L * DD + 255) / 256, 256, 0, stream>>>(b2, wb2, L * DD, flag);
  cvt_in<<<((L - 1) * DD + 255) / 256, 256, 0, stream>>>(gam, wgam, (L - 1) * DD, flag);
  cvt_in<<<((L - 1) * DD + 255) / 256, 256, 0, stream>>>(bet, wbet, (L - 1) * DD, flag);

  // one-time per call: tables, packed weights, CSR
  build_table<<<90, 256, 0, stream>>>(wee1, wee2, TBL);
  for (int l = 0; l < L; l++){
    pack_B<<<64, 256, 0, stream>>>(wW1 + (size_t)l * DD * 2 * DD,
                                   Wp1 + (size_t)l * DD * 2 * DD, DD, 2 * DD);
    pack_B<<<64, 256, 0, stream>>>(wW2 + (size_t)l * 2 * DD * DD,
                                   Wp2 + (size_t)l * 2 * DD * DD, 2 * DD, DD);
  }
  zero_int<<<(N + 255) / 256, 256, 0, stream>>>(counts, N);
  hist_kernel<<<(E + 255) / 256, 256, 0, stream>>>(ei + E, counts, E);
  scan_sums<<<NB, 256, 0, stream>>>(counts, bsum, N);
  scan_top<<<1, 64, 0, stream>>>(bsum, NB);
  scan_block<<<NB, 256, 0, stream>>>(counts, bsum, offsets, cursor, N);
  fill_csr<<<(E + 255) / 256, 256, 0, stream>>>(ei, ea, cursor, payload, E);

  // initial node features
  node_embed<<<(N * DD + 255) / 256, 256, 0, stream>>>(x, wx1, wx2, feat, N);

  int rpb_s = (N + SBLK - 1) / SBLK;
  float invN = 1.0f / (float)N;

  for (int l = 0; l < L; l++){
    aggregate<<<(N + 31) / 32, 256, 0, stream>>>(
        feat, TBL + (size_t)l * 18 * DD, offsets, counts, payload, agg, N);

    // chunked MLP: rows [r0, r0+CH)
    for (int r0 = 0; r0 < N; r0 += CH){
      int rows = N - r0; if (rows > CH) rows = CH;
      int gm = (rows + 127) / 128;
      // GEMM1: [rows,256] x [256,512] + b1, relu -> mid
      gemm_mfma<<<dim3(gm, 4), 256, 0, stream>>>(
          agg + (size_t)r0 * DD, Wp1 + (size_t)l * DD * 2 * DD,
          wb1 + (size_t)l * 2 * DD, mid, rows, DD, 2 * DD, 1);
      // GEMM2: [rows,512] x [512,256] + b2 -> h (into agg rows)
      gemm_mfma<<<dim3(gm, 2), 256, 0, stream>>>(
          mid, Wp2 + (size_t)l * 2 * DD * DD,
          wb2 + (size_t)l * DD, agg + (size_t)r0 * DD, rows, 2 * DD, DD, 0);
    }

    if (l < L - 1){
      bn_stats<<<SBLK, 256, 0, stream>>>(agg, part, N, rpb_s);
      bn_reduce<<<2, 256, 0, stream>>>(part, sums);
      bn_apply<<<1024, 256, 0, stream>>>(agg, sums, wgam + (size_t)l * DD,
                                         wbet + (size_t)l * DD, feat, N, invN);
    }
  }

  // final h is in agg; write to d_out in the proper dtype
  store_out<<<(N * DD + 255) / 256, 256, 0, stream>>>(agg, d_out, N * DD, flag);
}

// Round 3
// 1574.457 us; speedup vs baseline: 4.8234x; 1.1109x over previous
//
#include <hip/hip_runtime.h>

typedef unsigned short u16;
typedef unsigned int u32;

#define DD 256

typedef short  s16x8 __attribute__((ext_vector_type(8)));
typedef short  s16x4 __attribute__((ext_vector_type(4)));
typedef float  f32x4 __attribute__((ext_vector_type(4)));

__device__ __forceinline__ float b2f(u16 u){
  union { u32 i; float f; } c; c.i = ((u32)u) << 16; return c.f;
}
// round-to-nearest-even f32 -> bf16 (finite inputs)
__device__ __forceinline__ u16 f2b(float f){
  union { float f; u32 i; } c; c.f = f;
  u32 b = c.i + 0x7FFFu + ((c.i >> 16) & 1u);
  return (u16)(b >> 16);
}

// keep the harness's expected symbol name alive
__global__ void NodeEncoder_72971494359603_kernel(){}

// ---------------- dtype probe ----------------
__global__ void probe_dtype(const u32* w, u32* flag){
  if (threadIdx.x == 0 && blockIdx.x == 0){
    int cnt = 0;
    for (int i = 0; i < 256; i++){
      u32 low = w[i] & 0xFFFFu;
      u32 e = (low >> 7) & 0xFFu;
      if (e >= 0x60u && e <= 0x7Eu) cnt++;
    }
    *flag = (cnt >= 192) ? 1u : 0u;
  }
}

__global__ void cvt_in(const void* src, u16* dst, int n, const u32* flag){
  int i = blockIdx.x * 256 + threadIdx.x;
  if (i < n){
    if (*flag){
      dst[i] = ((const u16*)src)[i];
    } else {
      dst[i] = f2b(((const float*)src)[i]);
    }
  }
}

__global__ void store_out(const u16* h, void* dout, int n, const u32* flag){
  int i = blockIdx.x * 256 + threadIdx.x;
  if (i < n){
    if (*flag){
      ((u16*)dout)[i] = h[i];
    } else {
      ((float*)dout)[i] = b2f(h[i]);
    }
  }
}

// ---------------- utility ----------------
__global__ void zero_int(int* p, int n){
  int i = blockIdx.x * 256 + threadIdx.x;
  if (i < n) p[i] = 0;
}

// TBL[(l*18 + a*3 + b)*256 + j] = ee1[l][a][j] + ee2[l][b][j]   (f32)
__global__ void build_table(const u16* ee1, const u16* ee2, float* TBL){
  int b = blockIdx.x;               // 0..89
  int l = b / 18, c = b % 18, a = c / 3, bb = c % 3;
  int j = threadIdx.x;
  TBL[b * DD + j] = b2f(ee1[(l * 6 + a) * DD + j]) + b2f(ee2[(l * 3 + bb) * DD + j]);
}

// ---------------- CSR build ----------------
__global__ void hist_kernel(const int* dst, int* counts, int E){
  int e = blockIdx.x * 256 + threadIdx.x;
  if (e < E) atomicAdd(&counts[dst[e]], 1);
}

__global__ void scan_sums(const int* counts, int* bsum, int N){
  __shared__ int red[256];
  int tid = threadIdx.x;
  int base = blockIdx.x * 1024;
  int s = 0;
  for (int i = tid; i < 1024; i += 256){
    int g = base + i;
    if (g < N) s += counts[g];
  }
  red[tid] = s;
  __syncthreads();
  for (int off = 128; off > 0; off >>= 1){
    if (tid < off) red[tid] += red[tid + off];
    __syncthreads();
  }
  if (tid == 0) bsum[blockIdx.x] = red[0];
}

__global__ void scan_top(int* bsum, int nb){
  if (threadIdx.x == 0 && blockIdx.x == 0){
    int acc = 0;
    for (int i = 0; i < nb; i++){ int t = bsum[i]; bsum[i] = acc; acc += t; }
  }
}

__global__ void scan_block(const int* counts, const int* bsum,
                           int* offsets, int* cursor, int N){
  __shared__ int tsum[256];
  int b = blockIdx.x;
  int tid = threadIdx.x;
  int base = b * 1024;
  int v0, v1, v2, v3;
  int g = base + tid * 4;
  v0 = (g + 0 < N) ? counts[g + 0] : 0;
  v1 = (g + 1 < N) ? counts[g + 1] : 0;
  v2 = (g + 2 < N) ? counts[g + 2] : 0;
  v3 = (g + 3 < N) ? counts[g + 3] : 0;
  tsum[tid] = v0 + v1 + v2 + v3;
  __syncthreads();
  for (int off = 1; off < 256; off <<= 1){
    int t = (tid >= off) ? tsum[tid - off] : 0;
    __syncthreads();
    tsum[tid] += t;
    __syncthreads();
  }
  int excl = (tid == 0 ? 0 : tsum[tid - 1]) + bsum[b];
  if (g + 0 < N){ offsets[g + 0] = excl; cursor[g + 0] = excl; } excl += v0;
  if (g + 1 < N){ offsets[g + 1] = excl; cursor[g + 1] = excl; } excl += v1;
  if (g + 2 < N){ offsets[g + 2] = excl; cursor[g + 2] = excl; } excl += v2;
  if (g + 3 < N){ offsets[g + 3] = excl; cursor[g + 3] = excl; }
}

// payload[pos] = src | ((ea0*3+ea1) << 17)
__global__ void fill_csr(const int* ei, const int* ea, int* cursor,
                         int* payload, int E){
  int e = blockIdx.x * 256 + threadIdx.x;
  if (e < E){
    int d = ei[E + e];
    int pos = atomicAdd(&cursor[d], 1);
    int a = ea[2 * e], bb = ea[2 * e + 1];
    payload[pos] = ei[e] | ((a * 3 + bb) << 17);
  }
}

// ---------------- node embedding ----------------
__global__ void node_embed(const int* x, const u16* xe1, const u16* xe2,
                           u16* out, int N){
  int idx = blockIdx.x * 256 + threadIdx.x;
  if (idx < N * DD){
    int n = idx >> 8, j = idx & 255;
    int x0 = x[2 * n], x1 = x[2 * n + 1];
    out[idx] = f2b(b2f(xe1[x0 * DD + j]) + b2f(xe2[x1 * DD + j]));
  }
}

// ---------------- aggregation (CSR gather-sum, fused BN+relu) ----------------
// wave-per-node, lane handles 4 consecutive cols: 8B feature gathers,
// 16B LDS table reads. When apply_bn: source features are raw h of the
// previous layer; BN scale/shift + relu applied per gathered element.
__global__ void aggregate(const u16* __restrict__ feat, const float* __restrict__ TBL,
                          const int* __restrict__ offsets, const int* __restrict__ counts,
                          const int* __restrict__ payload, u16* __restrict__ agg, int N,
                          const float* __restrict__ sums, const u16* __restrict__ gamma,
                          const u16* __restrict__ beta, float invN, int apply_bn){
  __shared__ __align__(16) float T[18 * DD];
  int tid = threadIdx.x;
  for (int i = tid; i < 18 * DD; i += 256) T[i] = TBL[i];
  __syncthreads();
  int wave = tid >> 6, lane = tid & 63;
  int c4 = lane * 4;
  float sc[4], sh[4];
  if (apply_bn){
#pragma unroll
    for (int e = 0; e < 4; e++){
      int j = c4 + e;
      float mean = sums[j] * invN;
      float var = sums[DD + j] * invN - mean * mean;
      if (var < 0.f) var = 0.f;
      float scl = rsqrtf(var + 1e-5f) * b2f(gamma[j]);
      sc[e] = scl; sh[e] = b2f(beta[j]) - mean * scl;
    }
  } else {
#pragma unroll
    for (int e = 0; e < 4; e++){ sc[e] = 1.f; sh[e] = 0.f; }
  }
  int n0 = blockIdx.x * 32 + wave * 8;
  for (int u = 0; u < 8; u++){
    int n = n0 + u;
    if (n >= N) return;
    s16x4 sv = *(const s16x4*)(feat + (size_t)n * DD + c4);
    f32x4 tb = *(const f32x4*)(T + 12 * DD + c4);    // self-loop (4,0) -> idx 12
    float v0 = b2f((u16)sv[0]) * sc[0] + sh[0];
    float v1 = b2f((u16)sv[1]) * sc[1] + sh[1];
    float v2 = b2f((u16)sv[2]) * sc[2] + sh[2];
    float v3 = b2f((u16)sv[3]) * sc[3] + sh[3];
    if (apply_bn){
      v0 = fmaxf(v0, 0.f); v1 = fmaxf(v1, 0.f);
      v2 = fmaxf(v2, 0.f); v3 = fmaxf(v3, 0.f);
    }
    float a0 = v0 + tb[0], a1 = v1 + tb[1], a2 = v2 + tb[2], a3 = v3 + tb[3];
    int e0 = offsets[n], cnt = counts[n];
    for (int e = e0; e < e0 + cnt; e++){
      int pl = payload[e];
      int src = pl & 0x1FFFF;
      int idx = pl >> 17;
      s16x4 rv = *(const s16x4*)(feat + (size_t)src * DD + c4);
      f32x4 tv = *(const f32x4*)(T + idx * DD + c4);
      float w0 = b2f((u16)rv[0]) * sc[0] + sh[0];
      float w1 = b2f((u16)rv[1]) * sc[1] + sh[1];
      float w2 = b2f((u16)rv[2]) * sc[2] + sh[2];
      float w3 = b2f((u16)rv[3]) * sc[3] + sh[3];
      if (apply_bn){
        w0 = fmaxf(w0, 0.f); w1 = fmaxf(w1, 0.f);
        w2 = fmaxf(w2, 0.f); w3 = fmaxf(w3, 0.f);
      }
      a0 += w0 + tv[0];
      a1 += w1 + tv[1];
      a2 += w2 + tv[2];
      a3 += w3 + tv[3];
    }
    s16x4 o;
    o[0] = (short)f2b(a0); o[1] = (short)f2b(a1);
    o[2] = (short)f2b(a2); o[3] = (short)f2b(a3);
    *(s16x4*)(agg + (size_t)n * DD + c4) = o;
  }
}

// ---------------- B packing for MFMA fragments ----------------
// Wp chunk layout: frag = (cblk*(K/32) + ksub); lane l of frag holds
// W[ksub*32 + (l>>4)*8 + e][cblk*16 + (l&15)], e=0..7  (16B per lane,
// lane-contiguous -> one coalesced global_load_dwordx4 per b-frag).
__global__ void pack_B(const u16* __restrict__ W, u16* __restrict__ Wp, int K, int Nc){
  int idx = blockIdx.x * 256 + threadIdx.x;
  int lane = idx & 63;
  int t = idx >> 6;
  int nk = K >> 5;
  int ksub = t % nk, cblk = t / nk;
  if (cblk >= (Nc >> 4)) return;
  int col = cblk * 16 + (lane & 15);
  int krow = ksub * 32 + (lane >> 4) * 8;
  u16* dst = Wp + (size_t)idx * 8;
#pragma unroll
  for (int e = 0; e < 8; e++)
    dst[e] = W[(size_t)(krow + e) * Nc + col];
}

// ---------------- fused MLP: h = (relu(A@W1+b1))@W2 + b2 ----------------
// One block = 64 rows. 512 threads = 8 waves in 2 (row) x 4 (col).
// A-tile [64][256] staged once in LDS (XOR-swizzled 16B chunks).
// mid streamed in 4 chunks of 128 cols through a [64][128] LDS buffer
// (same swizzle); G1 writes it (C-layout, b16 stores), G2 consumes it as
// its A-operand via swizzled ds_read_b128. B operands from packed Wp
// fragments (L2-resident, one 16B coalesced load per frag).
__global__ void mlp_fused(const u16* __restrict__ A, const u16* __restrict__ Wp1,
                          const u16* __restrict__ bias1, const u16* __restrict__ Wp2,
                          const u16* __restrict__ bias2, u16* __restrict__ H, int M){
  __shared__ __align__(16) u16 As[64 * 256];   // 32 KB
  __shared__ __align__(16) u16 Ms[64 * 128];   // 16 KB
  int tid = threadIdx.x;
  int lane = tid & 63;
  int wave = tid >> 6;
  int wr = wave >> 2, wc = wave & 3;           // 2 x 4 wave grid
  int row0 = blockIdx.x * 64;
  int lrow = lane & 15;
  int lk8 = (lane >> 4) * 8;
  int r4 = (lane >> 4) * 4;

  // ---- stage A-tile: 64 rows x 256 cols (512B/row), swizzled ----
  int srow = tid >> 5, slot = tid & 31;        // 16 rows/pass, 32 chunks of 16B
#pragma unroll
  for (int p = 0; p < 4; p++){
    int r = p * 16 + srow;
    int gr = row0 + r; if (gr > M - 1) gr = M - 1;   // clamp; rows >= M never stored
    s16x8 v = *(const s16x8*)(A + (size_t)gr * DD + slot * 8);
    int byteo = r * 512 + ((slot * 16) ^ ((r & 7) << 4));
    *(s16x8*)((char*)As + byteo) = v;
  }

  f32x4 zero = {0.f, 0.f, 0.f, 0.f};
  f32x4 acc2[2][4];
#pragma unroll
  for (int m = 0; m < 2; m++)
#pragma unroll
    for (int n = 0; n < 4; n++) acc2[m][n] = zero;

  __syncthreads();

  for (int c = 0; c < 4; c++){                 // mid col chunks of 128
    // ---- G1: out[64 x 128chunk], wave does 32x32, K=256 ----
    f32x4 acc1[2][2];
#pragma unroll
    for (int m = 0; m < 2; m++)
#pragma unroll
      for (int n = 0; n < 2; n++) acc1[m][n] = zero;
#pragma unroll
    for (int ks = 0; ks < 8; ks++){
      s16x8 af[2], bf[2];
#pragma unroll
      for (int m = 0; m < 2; m++){
        int arow = wr * 32 + m * 16 + lrow;
        int byteo = arow * 512 + (((ks * 32 + lk8) * 2) ^ ((arow & 7) << 4));
        af[m] = *(const s16x8*)((const char*)As + byteo);
      }
#pragma unroll
      for (int n = 0; n < 2; n++){
        int cb = c * 8 + wc * 2 + n;           // midcol block (of 16)
        size_t fidx = ((size_t)cb * 8 + ks) * 64 + lane;
        bf[n] = *(const s16x8*)(Wp1 + fidx * 8);
      }
#pragma unroll
      for (int m = 0; m < 2; m++)
#pragma unroll
        for (int n = 0; n < 2; n++)
          acc1[m][n] = __builtin_amdgcn_mfma_f32_16x16x32_bf16(
              af[m], bf[n], acc1[m][n], 0, 0, 0);
    }
    __syncthreads();   // all waves done reading Ms (chunk c-1 G2 phase)
    // ---- bias1 + relu + bf16 -> Ms (chunk-local [64][128], swizzled) ----
#pragma unroll
    for (int n = 0; n < 2; n++){
      float bv = b2f(bias1[c * 128 + wc * 32 + n * 16 + lrow]);
      int colb = (wc * 32 + n * 16 + lrow) * 2;
#pragma unroll
      for (int m = 0; m < 2; m++){
#pragma unroll
        for (int r = 0; r < 4; r++){
          float v = acc1[m][n][r] + bv;
          if (v < 0.f) v = 0.f;
          int mrow = wr * 32 + m * 16 + r4 + r;
          int byteo = (mrow * 256 + colb) ^ ((mrow & 7) << 4);
          *(u16*)((char*)Ms + byteo) = f2b(v);
        }
      }
    }
    __syncthreads();   // mid chunk visible
    // ---- G2 partial: K-slice [c*128, c*128+128), 4 sub-k of 32 ----
#pragma unroll
    for (int ks = 0; ks < 4; ks++){
      s16x8 mf[2], wf[4];
#pragma unroll
      for (int m = 0; m < 2; m++){
        int mrow = wr * 32 + m * 16 + lrow;
        int byteo = mrow * 256 + (((ks * 32 + lk8) * 2) ^ ((mrow & 7) << 4));
        mf[m] = *(const s16x8*)((const char*)Ms + byteo);
      }
#pragma unroll
      for (int n = 0; n < 4; n++){
        int cb2 = wc * 4 + n;                  // out col block (of 16)
        size_t fidx = ((size_t)cb2 * 16 + c * 4 + ks) * 64 + lane;
        wf[n] = *(const s16x8*)(Wp2 + fidx * 8);
      }
#pragma unroll
      for (int m = 0; m < 2; m++)
#pragma unroll
        for (int n = 0; n < 4; n++)
          acc2[m][n] = __builtin_amdgcn_mfma_f32_16x16x32_bf16(
              mf[m], wf[n], acc2[m][n], 0, 0, 0);
    }
  }

  // ---- epilogue: bias2, bf16 store ----
  float bv2[4];
#pragma unroll
  for (int n = 0; n < 4; n++) bv2[n] = b2f(bias2[wc * 64 + n * 16 + lrow]);
#pragma unroll
  for (int m = 0; m < 2; m++){
    int rb = row0 + wr * 32 + m * 16 + r4;
#pragma unroll
    for (int r = 0; r < 4; r++){
      int row = rb + r;
      if (row >= M) continue;
      u16* cp = H + (size_t)row * DD + wc * 64 + lrow;
#pragma unroll
      for (int n = 0; n < 4; n++)
        cp[n * 16] = f2b(acc2[m][n][r] + bv2[n]);
    }
  }
}

// ---------------- BatchNorm stats ----------------
#define SBLK 256
__global__ void bn_stats(const u16* __restrict__ h, float* __restrict__ partial,
                         int N, int rpb){
  __shared__ float redS[8][256];
  __shared__ float redQ[8][256];
  int t = threadIdx.x;
  int rl = t >> 5, cg = (t & 31) * 8;
  int r0 = blockIdx.x * rpb;
  int r1 = r0 + rpb; if (r1 > N) r1 = N;
  float s[8], q[8];
#pragma unroll
  for (int e = 0; e < 8; e++){ s[e] = 0.f; q[e] = 0.f; }
  for (int r = r0 + rl; r < r1; r += 8){
    s16x8 v = *(const s16x8*)(h + (size_t)r * DD + cg);
#pragma unroll
    for (int e = 0; e < 8; e++){
      float f = b2f((u16)v[e]);
      s[e] += f; q[e] += f * f;
    }
  }
#pragma unroll
  for (int e = 0; e < 8; e++){ redS[rl][cg + e] = s[e]; redQ[rl][cg + e] = q[e]; }
  __syncthreads();
  float a = 0.f, b = 0.f;
#pragma unroll
  for (int k = 0; k < 8; k++){ a += redS[k][t]; b += redQ[k][t]; }
  partial[(size_t)blockIdx.x * DD + t] = a;
  partial[(size_t)(SBLK + blockIdx.x) * DD + t] = b;
}

__global__ void bn_reduce(const float* __restrict__ partial, float* __restrict__ sums){
  int j = threadIdx.x;
  int which = blockIdx.x;      // 0 = sum, 1 = sumsq
  float s = 0.f;
  for (int i = 0; i < SBLK; i++)
    s += partial[(size_t)(which * SBLK + i) * DD + j];
  sums[which * DD + j] = s;
}

// ---------------- host ----------------
extern "C" void kernel_launch(void* const* d_in, const int* in_sizes, int n_in,
                              void* d_out, int out_size, void* d_ws, size_t ws_size,
                              hipStream_t stream){
  (void)n_in; (void)out_size; (void)ws_size;
  const int* x    = (const int*)d_in[0];
  const int* ei   = (const int*)d_in[1];
  const int* ea   = (const int*)d_in[2];
  const void* xe1 = d_in[3];
  const void* xe2 = d_in[4];
  const void* ee1 = d_in[5];
  const void* ee2 = d_in[6];
  const void* W1  = d_in[7];
  const void* b1  = d_in[8];
  const void* W2  = d_in[9];
  const void* b2  = d_in[10];
  const void* gam = d_in[11];
  const void* bet = d_in[12];

  int N = in_sizes[0] / 2;
  int E = in_sizes[1] / 2;
  int NB = (N + 1023) / 1024;
  const int L = 5;

  // manual workspace carve (256B aligned)
  char* base = (char*)d_ws;
  size_t off = 0;
  u32* flag    = (u32*)(base + off);   off += 256;
  float* TBL   = (float*)(base + off); off += ((size_t)L * 18 * DD * 4 + 255) & ~(size_t)255;
  int* counts  = (int*)(base + off);   off += ((size_t)N * 4 + 255) & ~(size_t)255;
  int* offsets = (int*)(base + off);   off += ((size_t)N * 4 + 255) & ~(size_t)255;
  int* cursor  = (int*)(base + off);   off += ((size_t)N * 4 + 255) & ~(size_t)255;
  int* bsum    = (int*)(base + off);   off += ((size_t)NB * 4 + 255) & ~(size_t)255;
  int* payload = (int*)(base + off);   off += ((size_t)E * 4 + 255) & ~(size_t)255;
  float* part  = (float*)(base + off); off += ((size_t)2 * SBLK * DD * 4 + 255) & ~(size_t)255;
  float* sums  = (float*)(base + off); off += ((size_t)2 * DD * 4 + 255) & ~(size_t)255;
  // bf16 working copies of float inputs
  u16* wx1  = (u16*)(base + off); off += ((size_t)120 * DD * 2 + 255) & ~(size_t)255;
  u16* wx2  = (u16*)(base + off); off += ((size_t)3 * DD * 2 + 255) & ~(size_t)255;
  u16* wee1 = (u16*)(base + off); off += ((size_t)L * 6 * DD * 2 + 255) & ~(size_t)255;
  u16* wee2 = (u16*)(base + off); off += ((size_t)L * 3 * DD * 2 + 255) & ~(size_t)255;
  u16* wW1  = (u16*)(base + off); off += ((size_t)L * DD * 2 * DD * 2 + 255) & ~(size_t)255;
  u16* wb1  = (u16*)(base + off); off += ((size_t)L * 2 * DD * 2 + 255) & ~(size_t)255;
  u16* wW2  = (u16*)(base + off); off += ((size_t)L * 2 * DD * DD * 2 + 255) & ~(size_t)255;
  u16* wb2  = (u16*)(base + off); off += ((size_t)L * DD * 2 + 255) & ~(size_t)255;
  u16* wgam = (u16*)(base + off); off += ((size_t)(L - 1) * DD * 2 + 255) & ~(size_t)255;
  u16* wbet = (u16*)(base + off); off += ((size_t)(L - 1) * DD * 2 + 255) & ~(size_t)255;
  // packed MFMA B fragments
  u16* Wp1  = (u16*)(base + off); off += ((size_t)L * DD * 2 * DD * 2 + 255) & ~(size_t)255;
  u16* Wp2  = (u16*)(base + off); off += ((size_t)L * 2 * DD * DD * 2 + 255) & ~(size_t)255;
  // big feature buffers (bf16)
  u16* feat = (u16*)(base + off); off += ((size_t)N * DD * 2 + 255) & ~(size_t)255;
  u16* agg  = (u16*)(base + off); off += ((size_t)N * DD * 2 + 255) & ~(size_t)255;

  // dtype probe + input conversion to bf16 working copies
  probe_dtype<<<1, 64, 0, stream>>>((const u32*)xe1, flag);
  cvt_in<<<(120 * DD + 255) / 256, 256, 0, stream>>>(xe1, wx1, 120 * DD, flag);
  cvt_in<<<(3 * DD + 255) / 256, 256, 0, stream>>>(xe2, wx2, 3 * DD, flag);
  cvt_in<<<(L * 6 * DD + 255) / 256, 256, 0, stream>>>(ee1, wee1, L * 6 * DD, flag);
  cvt_in<<<(L * 3 * DD + 255) / 256, 256, 0, stream>>>(ee2, wee2, L * 3 * DD, flag);
  cvt_in<<<(L * DD * 2 * DD + 255) / 256, 256, 0, stream>>>(W1, wW1, L * DD * 2 * DD, flag);
  cvt_in<<<(L * 2 * DD + 255) / 256, 256, 0, stream>>>(b1, wb1, L * 2 * DD, flag);
  cvt_in<<<(L * 2 * DD * DD + 255) / 256, 256, 0, stream>>>(W2, wW2, L * 2 * DD * DD, flag);
  cvt_in<<<(L * DD + 255) / 256, 256, 0, stream>>>(b2, wb2, L * DD, flag);
  cvt_in<<<((L - 1) * DD + 255) / 256, 256, 0, stream>>>(gam, wgam, (L - 1) * DD, flag);
  cvt_in<<<((L - 1) * DD + 255) / 256, 256, 0, stream>>>(bet, wbet, (L - 1) * DD, flag);

  // one-time per call: tables, packed weights, CSR
  build_table<<<90, 256, 0, stream>>>(wee1, wee2, TBL);
  for (int l = 0; l < L; l++){
    pack_B<<<64, 256, 0, stream>>>(wW1 + (size_t)l * DD * 2 * DD,
                                   Wp1 + (size_t)l * DD * 2 * DD, DD, 2 * DD);
    pack_B<<<64, 256, 0, stream>>>(wW2 + (size_t)l * 2 * DD * DD,
                                   Wp2 + (size_t)l * 2 * DD * DD, 2 * DD, DD);
  }
  zero_int<<<(N + 255) / 256, 256, 0, stream>>>(counts, N);
  hist_kernel<<<(E + 255) / 256, 256, 0, stream>>>(ei + E, counts, E);
  scan_sums<<<NB, 256, 0, stream>>>(counts, bsum, N);
  scan_top<<<1, 64, 0, stream>>>(bsum, NB);
  scan_block<<<NB, 256, 0, stream>>>(counts, bsum, offsets, cursor, N);
  fill_csr<<<(E + 255) / 256, 256, 0, stream>>>(ei, ea, cursor, payload, E);

  // initial node features
  node_embed<<<(N * DD + 255) / 256, 256, 0, stream>>>(x, wx1, wx2, feat, N);

  int rpb_s = (N + SBLK - 1) / SBLK;
  float invN = 1.0f / (float)N;

  for (int l = 0; l < L; l++){
    // aggregate reads feat (embed for l=0; raw h for l>0, BN+relu fused)
    aggregate<<<(N + 31) / 32, 256, 0, stream>>>(
        feat, TBL + (size_t)l * 18 * DD, offsets, counts, payload, agg, N,
        sums, wgam + (size_t)(l > 0 ? l - 1 : 0) * DD,
        wbet + (size_t)(l > 0 ? l - 1 : 0) * DD, invN, l > 0 ? 1 : 0);

    // fused MLP: agg -> h (into feat)
    mlp_fused<<<(N + 63) / 64, 512, 0, stream>>>(
        agg, Wp1 + (size_t)l * DD * 2 * DD, wb1 + (size_t)l * 2 * DD,
        Wp2 + (size_t)l * 2 * DD * DD, wb2 + (size_t)l * DD, feat, N);

    if (l < L - 1){
      bn_stats<<<SBLK, 256, 0, stream>>>(feat, part, N, rpb_s);
      bn_reduce<<<2, 256, 0, stream>>>(part, sums);
    }
  }

  // final h is in feat; write to d_out in the proper dtype
  store_out<<<(N * DD + 255) / 256, 256, 0, stream>>>(feat, d_out, N * DD, flag);
}